// Round 2
// baseline (1563.620 us; speedup 1.0000x reference)
//
#include <hip/hip_runtime.h>

#define B_   32
#define C_   256
#define HW_  4096
#define N_   131072   // B*H*W rows
#define K_   1024     // codebook size
#define BM   128
#define BN   128
#define BC   32
#define LSTR 36       // padded LDS row stride (floats); 144B ≡ 16 mod 128 -> conflict-free b128

// ---------------- ||e_k||^2, replicating numpy pairwise_sum(256) ----------------
__global__ void ee_kernel(const float* __restrict__ emb, float* __restrict__ ee) {
#pragma clang fp contract(off)
    int k = blockIdx.x * blockDim.x + threadIdx.x;
    if (k >= K_) return;
    const float* e = emb + (size_t)k * C_;
    float res = 0.f;
    for (int h = 0; h < 2; ++h) {              // numpy: pairwise(0:128) + pairwise(128:256)
        float r[8];
        #pragma unroll
        for (int j = 0; j < 8; ++j) { float v = e[h*128 + j]; r[j] = v * v; }
        for (int i = 8; i < 128; i += 8) {
            #pragma unroll
            for (int j = 0; j < 8; ++j) { float v = e[h*128 + i + j]; r[j] += v * v; }
        }
        float s = ((r[0] + r[1]) + (r[2] + r[3])) + ((r[4] + r[5]) + (r[6] + r[7]));
        res += s;
    }
    ee[k] = res;
}

// ---------------- ||z_n||^2, same pairwise structure, coalesced along hw ----------------
__global__ void zz_kernel(const float* __restrict__ z, float* __restrict__ zz) {
#pragma clang fp contract(off)
    int n = blockIdx.x * blockDim.x + threadIdx.x;
    if (n >= N_) return;
    int b = n >> 12, hw = n & 4095;
    const float* zp = z + (size_t)b * C_ * HW_ + hw;
    float res = 0.f;
    for (int h = 0; h < 2; ++h) {
        float r[8];
        #pragma unroll
        for (int j = 0; j < 8; ++j) { float v = zp[(size_t)(h*128 + j) * HW_]; r[j] = v * v; }
        for (int i = 8; i < 128; i += 8) {
            #pragma unroll
            for (int j = 0; j < 8; ++j) { float v = zp[(size_t)(h*128 + i + j) * HW_]; r[j] += v * v; }
        }
        float s = ((r[0] + r[1]) + (r[2] + r[3])) + ((r[4] + r[5]) + (r[6] + r[7]));
        res += s;
    }
    zz[n] = res;
}

// ---------------- distance GEMM + argmin ----------------
__launch_bounds__(256)
__global__ void argmin_kernel(const float* __restrict__ z, const float* __restrict__ emb,
                              const float* __restrict__ zz, const float* __restrict__ ee,
                              int* __restrict__ idx_i, float* __restrict__ idx_f) {
    __shared__ float smem[(BM + BN) * LSTR];       // 36.9 KB
    float* zt = smem;
    float* et = smem + BM * LSTR;

    const int tid = threadIdx.x;
    const int tc = tid & 15, tr = tid >> 4;        // 16x16 thread grid
    const int row0 = blockIdx.x * BM;
    const int b = row0 >> 12;
    const int hw0 = row0 & 4095;                   // 128 | 4096 -> block stays in one b
    const float* zbase = z + (size_t)b * C_ * HW_ + hw0;

    float zzr[8];
    #pragma unroll
    for (int m = 0; m < 8; ++m) zzr[m] = zz[row0 + tr + 16*m];

    float bestv[8]; int besti[8];
    #pragma unroll
    for (int m = 0; m < 8; ++m) { bestv[m] = 3.4e38f; besti[m] = 0; }

    for (int kt = 0; kt < K_/BN; ++kt) {
        float acc[8][8];
        #pragma unroll
        for (int m = 0; m < 8; ++m)
            #pragma unroll
            for (int n = 0; n < 8; ++n) acc[m][n] = 0.f;

        for (int c0 = 0; c0 < C_; c0 += BC) {
            // stage z tile [128 rows][32 c]: gather 4 strided c per lane -> b128 write
            #pragma unroll
            for (int p = 0; p < 4; ++p) {
                int g = tid + 256*p;
                int r = g & 127, c4 = g >> 7;
                const float* src = zbase + (size_t)(c0 + c4*4) * HW_ + r;
                float4 v;
                v.x = src[0*HW_]; v.y = src[1*HW_]; v.z = src[2*HW_]; v.w = src[3*HW_];
                *(float4*)&zt[r*LSTR + c4*4] = v;
            }
            // stage e tile [128 codes][32 c]: contiguous float4
            #pragma unroll
            for (int p = 0; p < 4; ++p) {
                int g = tid + 256*p;
                int r = g & 127, c4 = g >> 7;
                float4 v = *(const float4*)&emb[(size_t)(kt*BN + r) * C_ + c0 + c4*4];
                *(float4*)&et[r*LSTR + c4*4] = v;
            }
            __syncthreads();
            #pragma unroll
            for (int cc4 = 0; cc4 < BC/4; ++cc4) {
                float4 a[8], bb[8];
                #pragma unroll
                for (int m = 0; m < 8; ++m) a[m]  = *(const float4*)&zt[(tr + 16*m)*LSTR + cc4*4];
                #pragma unroll
                for (int n = 0; n < 8; ++n) bb[n] = *(const float4*)&et[(tc + 16*n)*LSTR + cc4*4];
                #pragma unroll
                for (int m = 0; m < 8; ++m)
                    #pragma unroll
                    for (int n = 0; n < 8; ++n) {
                        acc[m][n] += a[m].x * bb[n].x;
                        acc[m][n] += a[m].y * bb[n].y;
                        acc[m][n] += a[m].z * bb[n].z;
                        acc[m][n] += a[m].w * bb[n].w;
                    }
            }
            __syncthreads();
        }
        // d = R(R(zz+ee) - 2*dot)  -- replicates numpy's rounding (2*dot exact)
        #pragma unroll
        for (int n = 0; n < 8; ++n) {
            int kk = kt*BN + tc + 16*n;
            float eev = ee[kk];
            #pragma unroll
            for (int m = 0; m < 8; ++m) {
                float A = zzr[m] + eev;
                float d = A - 2.0f * acc[m][n];
                if (d < bestv[m] || (d == bestv[m] && kk < besti[m])) { bestv[m] = d; besti[m] = kk; }
            }
        }
    }

    // reduce (val,idx) lexicographically across the 16 tc-threads per row
    __syncthreads();
    float2* red = (float2*)smem;                   // [BM][16]
    #pragma unroll
    for (int m = 0; m < 8; ++m)
        red[(tr + 16*m)*16 + tc] = make_float2(bestv[m], (float)besti[m]);
    __syncthreads();
    if (tid < BM) {
        int r = tid;
        float bv = 3.4e38f; int bi = 0;
        for (int t = 0; t < 16; ++t) {
            float2 e2 = red[r*16 + t];
            int ii = (int)e2.y;
            if (e2.x < bv || (e2.x == bv && ii < bi)) { bv = e2.x; bi = ii; }
        }
        idx_i[row0 + r] = bi;
        idx_f[row0 + r] = (float)bi;
    }
}

// ---------------- gather zq_st (straight-through, transposed to [B,C,H,W]) + loss partials ----------------
__global__ void gather_kernel(const float* __restrict__ z, const float* __restrict__ emb,
                              const int* __restrict__ idx, float* __restrict__ zq,
                              float* __restrict__ partials) {
#pragma clang fp contract(off)
    const long long TOT = (long long)N_ * (C_/4);  // (n, c4) pairs
    float ls = 0.f;
    for (long long g = (long long)blockIdx.x * blockDim.x + threadIdx.x; g < TOT;
         g += (long long)gridDim.x * blockDim.x) {
        int c4 = (int)(g >> 17);                   // 0..63
        int n  = (int)(g & (N_ - 1));
        int b = n >> 12, hw = n & 4095;
        int j = idx[n];
        float4 e4 = *(const float4*)&emb[(size_t)j * C_ + c4*4];
        size_t base = (size_t)b * C_ * HW_ + (size_t)(c4*4) * HW_ + hw;
        // zq_st = R(zp + R(zq - zp)) exactly as the reference; loss uses (zq - zp)^2
        float zv, df;
        zv = z[base + 0*HW_]; df = e4.x - zv; zq[base + 0*HW_] = zv + df; ls += df*df;
        zv = z[base + 1*HW_]; df = e4.y - zv; zq[base + 1*HW_] = zv + df; ls += df*df;
        zv = z[base + 2*HW_]; df = e4.z - zv; zq[base + 2*HW_] = zv + df; ls += df*df;
        zv = z[base + 3*HW_]; df = e4.w - zv; zq[base + 3*HW_] = zv + df; ls += df*df;
    }
    __shared__ float sred[256];
    sred[threadIdx.x] = ls;
    __syncthreads();
    for (int s = 128; s > 0; s >>= 1) {
        if (threadIdx.x < s) sred[threadIdx.x] += sred[threadIdx.x + s];
        __syncthreads();
    }
    if (threadIdx.x == 0) partials[blockIdx.x] = sred[0];
}

__global__ void finalize_kernel(const float* __restrict__ partials, int nparts,
                                float* __restrict__ loss_out) {
    __shared__ float sred[256];
    float s = 0.f;
    for (int i = threadIdx.x; i < nparts; i += 256) s += partials[i];
    sred[threadIdx.x] = s; __syncthreads();
    for (int st = 128; st > 0; st >>= 1) {
        if (threadIdx.x < st) sred[threadIdx.x] += sred[threadIdx.x + st];
        __syncthreads();
    }
    if (threadIdx.x == 0) {
        float m = sred[0] / 33554432.0f;   // mean((zq - z)^2)
        *loss_out = m - 0.25f * m;         // mse - beta*mse, mirroring ref's rounding
    }
}

extern "C" void kernel_launch(void* const* d_in, const int* in_sizes, int n_in,
                              void* d_out, int out_size, void* d_ws, size_t ws_size,
                              hipStream_t stream) {
    const float* z   = (const float*)d_in[0];
    const float* emb = (const float*)d_in[1];
    float* out   = (float*)d_out;
    float* zq    = out;                        // 33554432
    float* idx_f = out + (size_t)N_ * C_;      // 131072 (idx stored as float)
    float* loss  = idx_f + N_;                 // 1

    float* zz       = (float*)d_ws;            // N_
    float* ee       = zz + N_;                  // K_
    int*   idx_i    = (int*)(ee + K_);          // N_
    float* partials = (float*)(idx_i + N_);     // 2048

    ee_kernel<<<(K_ + 255)/256, 256, 0, stream>>>(emb, ee);
    zz_kernel<<<N_/256, 256, 0, stream>>>(z, zz);
    argmin_kernel<<<N_/BM, 256, 0, stream>>>(z, emb, zz, ee, idx_i, idx_f);
    gather_kernel<<<2048, 256, 0, stream>>>(z, emb, idx_i, zq, partials);
    finalize_kernel<<<1, 256, 0, stream>>>(partials, 2048, loss);
}

// Round 4
// 799.616 us; speedup vs baseline: 1.9555x; 1.9555x over previous
//
#include <hip/hip_runtime.h>
#include <stdint.h>

#define B_   32
#define C_   256
#define HW_  4096
#define N_   131072   // B*H*W rows
#define K_   1024     // codebook size

typedef __attribute__((ext_vector_type(8))) short bf16x8;
typedef __attribute__((ext_vector_type(4))) float f32x4;

__device__ __forceinline__ unsigned short f2bf(float f) {
    unsigned int x = __float_as_uint(f);
    return (unsigned short)((x + 0x7FFFu + ((x >> 16) & 1u)) >> 16);   // RNE
}
__device__ __forceinline__ float bf2f(unsigned short h) {
    return __uint_as_float(((unsigned int)h) << 16);
}

#define GLD16(g, l) __builtin_amdgcn_global_load_lds((const __attribute__((address_space(1))) void*)(g), \
                        (__attribute__((address_space(3))) void*)(l), 16, 0, 0)

// ---------------- ||e_k||^2, replicating numpy pairwise_sum(256) ----------------
__global__ void ee_kernel(const float* __restrict__ emb, float* __restrict__ ee) {
#pragma clang fp contract(off)
    int k = blockIdx.x * blockDim.x + threadIdx.x;
    if (k >= K_) return;
    const float* e = emb + (size_t)k * C_;
    float res = 0.f;
    for (int h = 0; h < 2; ++h) {
        float r[8];
        #pragma unroll
        for (int j = 0; j < 8; ++j) { float v = e[h*128 + j]; r[j] = v * v; }
        for (int i = 8; i < 128; i += 8) {
            #pragma unroll
            for (int j = 0; j < 8; ++j) { float v = e[h*128 + i + j]; r[j] += v * v; }
        }
        float s = ((r[0] + r[1]) + (r[2] + r[3])) + ((r[4] + r[5]) + (r[6] + r[7]));
        res += s;
    }
    ee[k] = res;
}

// ---------------- ||z_n||^2, same pairwise structure ----------------
__global__ void zz_kernel(const float* __restrict__ z, float* __restrict__ zz) {
#pragma clang fp contract(off)
    int n = blockIdx.x * blockDim.x + threadIdx.x;
    if (n >= N_) return;
    int b = n >> 12, hw = n & 4095;
    const float* zp = z + (size_t)b * C_ * HW_ + hw;
    float res = 0.f;
    for (int h = 0; h < 2; ++h) {
        float r[8];
        #pragma unroll
        for (int j = 0; j < 8; ++j) { float v = zp[(size_t)(h*128 + j) * HW_]; r[j] = v * v; }
        for (int i = 8; i < 128; i += 8) {
            #pragma unroll
            for (int j = 0; j < 8; ++j) { float v = zp[(size_t)(h*128 + i + j) * HW_]; r[j] += v * v; }
        }
        float s = ((r[0] + r[1]) + (r[2] + r[3])) + ((r[4] + r[5]) + (r[6] + r[7]));
        res += s;
    }
    zz[n] = res;
}

// ---------------- emb -> bf16 hi/lo split, [k][c] layout ----------------
__global__ void esplit_kernel(const float* __restrict__ emb,
                              unsigned short* __restrict__ eh, unsigned short* __restrict__ el) {
    int t = blockIdx.x * 256 + threadIdx.x;            // 32768 threads
    int k = t >> 5, c8 = (t & 31) * 8;
    const float* src = emb + (size_t)k * C_ + c8;
    unsigned short hb[8], lb[8];
    #pragma unroll
    for (int i = 0; i < 8; ++i) {
        float f = src[i];
        unsigned short h = f2bf(f);
        hb[i] = h; lb[i] = f2bf(f - bf2f(h));
    }
    size_t off = (size_t)k * C_ + c8;
    *(uint4*)&eh[off] = *(uint4*)hb;
    *(uint4*)&el[off] = *(uint4*)lb;
}

// ---------------- z -> bf16 hi/lo split, TRANSPOSED to [n][c] layout ----------------
__global__ void zsplit_kernel(const float* __restrict__ z,
                              unsigned short* __restrict__ zh, unsigned short* __restrict__ zl) {
    __shared__ float t[64][65];
    int blk = blockIdx.x;
    int b = blk >> 8, ct = (blk >> 6) & 3, ht = blk & 63;
    int tid = threadIdx.x;
    int hw = tid & 63, c0 = tid >> 6;
    const float* src = z + ((size_t)b * C_ + ct * 64) * HW_ + ht * 64;
    #pragma unroll
    for (int k = 0; k < 16; ++k) {
        int c = k * 4 + c0;
        t[c][hw] = src[(size_t)c * HW_ + hw];
    }
    __syncthreads();
    int hw2 = tid >> 2, cs = (tid & 3) * 16;
    size_t off = ((size_t)b * HW_ + ht * 64 + hw2) * C_ + ct * 64 + cs;
    unsigned short hb[16], lb[16];
    #pragma unroll
    for (int i = 0; i < 16; ++i) {
        float f = t[cs + i][hw2];
        unsigned short h = f2bf(f);
        hb[i] = h; lb[i] = f2bf(f - bf2f(h));
    }
    *(uint4*)&zh[off]     = *(uint4*)&hb[0];
    *(uint4*)&zh[off + 8] = *(uint4*)&hb[8];
    *(uint4*)&zl[off]     = *(uint4*)&lb[0];
    *(uint4*)&zl[off + 8] = *(uint4*)&lb[8];
}

// ---------------- MFMA approx-distance + per-row top-3 shortlist ----------------
#define INS3(T, P) do { uint32_t _p = (P); \
    if (_p < T[2]) { if (_p < T[1]) { T[2] = T[1]; \
        if (_p < T[0]) { T[1] = T[0]; T[0] = _p; } else T[1] = _p; } else T[2] = _p; } } while (0)

__launch_bounds__(256)
__global__ void mfma_argmin_kernel(const unsigned short* __restrict__ zh, const unsigned short* __restrict__ zl,
                                   const unsigned short* __restrict__ eh, const unsigned short* __restrict__ el,
                                   const float* __restrict__ ee, uint32_t* __restrict__ top3) {
    __shared__ unsigned short Ah[128*32], Al[128*32], Bh[128*32], Bl[128*32];  // 32 KB
    __shared__ float eesh[K_];                                                 // 4 KB
    __shared__ uint32_t red[128][2][3];                                        // 3 KB

    const int tid = threadIdx.x;
    const int lane = tid & 63, wave = tid >> 6;
    const int wr = wave >> 1, wc = wave & 1;
    const int row0 = blockIdx.x * 128;

    for (int i = tid; i < K_; i += 256) eesh[i] = ee[i];

    uint32_t t3[16][3];
    #pragma unroll
    for (int s = 0; s < 16; ++s) { t3[s][0] = 0xFFFFFFFFu; t3[s][1] = 0xFFFFFFFFu; t3[s][2] = 0xFFFFFFFFu; }

    const int lr  = lane >> 2;          // staging: row within 16-row group
    const int lc8 = (lane & 3) * 8;     // staging: ushort col offset (16 B)
    const int fr  = lane & 15;          // frag row/col
    const int fk  = (lane >> 4) * 8;    // frag k offset (8 bf16)
    const int rb  = wave * 32;          // this wave's 32-row staging slice

    __syncthreads();                    // eesh ready

    for (int kt = 0; kt < 8; ++kt) {
        f32x4 acc[4][4];
        #pragma unroll
        for (int m = 0; m < 4; ++m)
            #pragma unroll
            for (int n = 0; n < 4; ++n) acc[m][n] = (f32x4){0.f, 0.f, 0.f, 0.f};

        for (int c0 = 0; c0 < C_; c0 += 32) {
            size_t ga0 = (size_t)(row0 + rb + lr) * C_ + c0 + lc8;
            size_t ga1 = ga0 + (size_t)16 * C_;
            size_t gb0 = (size_t)(kt * 128 + rb + lr) * C_ + c0 + lc8;
            size_t gb1 = gb0 + (size_t)16 * C_;
            GLD16(zh + ga0, &Ah[(rb +  0) * 32]);
            GLD16(zh + ga1, &Ah[(rb + 16) * 32]);
            GLD16(zl + ga0, &Al[(rb +  0) * 32]);
            GLD16(zl + ga1, &Al[(rb + 16) * 32]);
            GLD16(eh + gb0, &Bh[(rb +  0) * 32]);
            GLD16(eh + gb1, &Bh[(rb + 16) * 32]);
            GLD16(el + gb0, &Bl[(rb +  0) * 32]);
            GLD16(el + gb1, &Bl[(rb + 16) * 32]);
            __syncthreads();

            bf16x8 ah[4], al4[4], bh[4], bl4[4];
            #pragma unroll
            for (int m = 0; m < 4; ++m) {
                int r = wr * 64 + m * 16 + fr;
                ah[m]  = *(const bf16x8*)&Ah[r * 32 + fk];
                al4[m] = *(const bf16x8*)&Al[r * 32 + fk];
            }
            #pragma unroll
            for (int n = 0; n < 4; ++n) {
                int r = wc * 64 + n * 16 + fr;
                bh[n]  = *(const bf16x8*)&Bh[r * 32 + fk];
                bl4[n] = *(const bf16x8*)&Bl[r * 32 + fk];
            }
            #pragma unroll
            for (int m = 0; m < 4; ++m)
                #pragma unroll
                for (int n = 0; n < 4; ++n) {
                    acc[m][n] = __builtin_amdgcn_mfma_f32_16x16x32_bf16(ah[m],  bh[n],  acc[m][n], 0, 0, 0);
                    acc[m][n] = __builtin_amdgcn_mfma_f32_16x16x32_bf16(ah[m],  bl4[n], acc[m][n], 0, 0, 0);
                    acc[m][n] = __builtin_amdgcn_mfma_f32_16x16x32_bf16(al4[m], bh[n],  acc[m][n], 0, 0, 0);
                }
            __syncthreads();
        }

        // epilogue: d' = ee[col] - 2*dot, pack (sortable-float | col), keep per-row top3
        #pragma unroll
        for (int n = 0; n < 4; ++n) {
            int col = kt * 128 + wc * 64 + n * 16 + fr;
            float eev = eesh[col];
            #pragma unroll
            for (int m = 0; m < 4; ++m) {
                #pragma unroll
                for (int j = 0; j < 4; ++j) {
                    float d = eev - 2.0f * acc[m][n][j];
                    uint32_t bbits = __float_as_uint(d);
                    uint32_t u = bbits ^ (0x80000000u | (uint32_t)((int32_t)bbits >> 31));
                    uint32_t p = (u & 0xFFFFFC00u) | (uint32_t)col;
                    INS3(t3[m * 4 + j], p);
                }
            }
        }
    }

    // butterfly-merge top3 across the 16 lanes sharing each row
    #pragma unroll
    for (int st = 1; st < 16; st <<= 1) {
        #pragma unroll
        for (int s = 0; s < 16; ++s) {
            uint32_t q0 = __shfl_xor(t3[s][0], st, 64);
            uint32_t q1 = __shfl_xor(t3[s][1], st, 64);
            uint32_t q2 = __shfl_xor(t3[s][2], st, 64);
            INS3(t3[s], q0); INS3(t3[s], q1); INS3(t3[s], q2);
        }
    }
    if ((lane & 15) == 0) {
        int g = lane >> 4;
        #pragma unroll
        for (int m = 0; m < 4; ++m)
            #pragma unroll
            for (int j = 0; j < 4; ++j) {
                int r = wr * 64 + m * 16 + g * 4 + j;
                int s = m * 4 + j;
                red[r][wc][0] = t3[s][0]; red[r][wc][1] = t3[s][1]; red[r][wc][2] = t3[s][2];
            }
    }
    __syncthreads();
    if (tid < 128) {
        uint32_t a0 = red[tid][0][0], a1 = red[tid][0][1], a2 = red[tid][0][2];
        uint32_t b0 = red[tid][1][0], b1 = red[tid][1][1], b2 = red[tid][1][2];
        uint32_t o0, o1, o2;
        if (a0 <= b0) { o0 = a0;
            if (a1 <= b0) { o1 = a1; o2 = (a2 < b0 ? a2 : b0); }
            else          { o1 = b0; o2 = (a1 < b1 ? a1 : b1); }
        } else { o0 = b0;
            if (b1 <= a0) { o1 = b1; o2 = (b2 < a0 ? b2 : a0); }
            else          { o1 = a0; o2 = (a1 < b1 ? a1 : b1); }
        }
        uint32_t* dst = top3 + (size_t)(row0 + tid) * 3;
        dst[0] = o0; dst[1] = o1; dst[2] = o2;
    }
}

// ---------------- exact refine on top-3 (bit-replicates round-2 arithmetic) ----------------
__global__ void refine_kernel(const float* __restrict__ z, const float* __restrict__ emb,
                              const float* __restrict__ zz, const float* __restrict__ ee,
                              const uint32_t* __restrict__ top3,
                              int* __restrict__ idx_i, float* __restrict__ idx_f) {
    int n = blockIdx.x * 256 + threadIdx.x;
    int b = n >> 12, hw = n & 4095;
    int c0 = (int)(top3[(size_t)n * 3 + 0] & 0x3FFu);
    int c1 = (int)(top3[(size_t)n * 3 + 1] & 0x3FFu);
    int c2 = (int)(top3[(size_t)n * 3 + 2] & 0x3FFu);
    int t;
    if (c1 < c0) { t = c0; c0 = c1; c1 = t; }
    if (c2 < c1) { t = c1; c1 = c2; c2 = t; }
    if (c1 < c0) { t = c0; c0 = c1; c1 = t; }
    const float* zp = z + (size_t)b * C_ * HW_ + hw;
    const float* e0 = emb + (size_t)c0 * C_;
    const float* e1 = emb + (size_t)c1 * C_;
    const float* e2 = emb + (size_t)c2 * C_;
    float a0 = 0.f, a1 = 0.f, a2 = 0.f;
    for (int c = 0; c < C_; ++c) {
        float zv = zp[(size_t)c * HW_];
        a0 = fmaf(zv, e0[c], a0);
        a1 = fmaf(zv, e1[c], a1);
        a2 = fmaf(zv, e2[c], a2);
    }
    float zzr = zz[n];
    float A0 = zzr + ee[c0]; float d0 = A0 - 2.0f * a0;
    float A1 = zzr + ee[c1]; float d1 = A1 - 2.0f * a1;
    float A2 = zzr + ee[c2]; float d2 = A2 - 2.0f * a2;
    float bv = d0; int bi = c0;
    if (c1 != c0 && d1 < bv) { bv = d1; bi = c1; }
    if (c2 != c1 && c2 != c0 && d2 < bv) { bv = d2; bi = c2; }
    idx_i[n] = bi;
    idx_f[n] = (float)bi;
}

// ---------------- gather zq_st (straight-through) + loss partials ----------------
__global__ void gather_kernel(const float* __restrict__ z, const float* __restrict__ emb,
                              const int* __restrict__ idx, float* __restrict__ zq,
                              float* __restrict__ partials) {
#pragma clang fp contract(off)
    const long long TOT = (long long)N_ * (C_/4);
    float ls = 0.f;
    for (long long g = (long long)blockIdx.x * blockDim.x + threadIdx.x; g < TOT;
         g += (long long)gridDim.x * blockDim.x) {
        int c4 = (int)(g >> 17);
        int n  = (int)(g & (N_ - 1));
        int b = n >> 12, hw = n & 4095;
        int j = idx[n];
        float4 e4 = *(const float4*)&emb[(size_t)j * C_ + c4*4];
        size_t base = (size_t)b * C_ * HW_ + (size_t)(c4*4) * HW_ + hw;
        float zv, df;
        zv = z[base + 0*HW_]; df = e4.x - zv; zq[base + 0*HW_] = zv + df; ls += df*df;
        zv = z[base + 1*HW_]; df = e4.y - zv; zq[base + 1*HW_] = zv + df; ls += df*df;
        zv = z[base + 2*HW_]; df = e4.z - zv; zq[base + 2*HW_] = zv + df; ls += df*df;
        zv = z[base + 3*HW_]; df = e4.w - zv; zq[base + 3*HW_] = zv + df; ls += df*df;
    }
    __shared__ float sred[256];
    sred[threadIdx.x] = ls;
    __syncthreads();
    for (int s = 128; s > 0; s >>= 1) {
        if (threadIdx.x < s) sred[threadIdx.x] += sred[threadIdx.x + s];
        __syncthreads();
    }
    if (threadIdx.x == 0) partials[blockIdx.x] = sred[0];
}

__global__ void finalize_kernel(const float* __restrict__ partials, int nparts,
                                float* __restrict__ loss_out) {
    __shared__ float sred[256];
    float s = 0.f;
    for (int i = threadIdx.x; i < nparts; i += 256) s += partials[i];
    sred[threadIdx.x] = s; __syncthreads();
    for (int st = 128; st > 0; st >>= 1) {
        if (threadIdx.x < st) sred[threadIdx.x] += sred[threadIdx.x + st];
        __syncthreads();
    }
    if (threadIdx.x == 0) {
        float m = sred[0] / 33554432.0f;
        *loss_out = m - 0.25f * m;
    }
}

extern "C" void kernel_launch(void* const* d_in, const int* in_sizes, int n_in,
                              void* d_out, int out_size, void* d_ws, size_t ws_size,
                              hipStream_t stream) {
    const float* z   = (const float*)d_in[0];
    const float* emb = (const float*)d_in[1];
    float* out   = (float*)d_out;
    float* zq    = out;                        // 33554432 floats
    float* idx_f = out + (size_t)N_ * C_;      // 131072
    float* loss  = idx_f + N_;                 // 1

    // zh/zl (bf16, [n][c]) live in the zq region (exactly 134 MB); gather overwrites later.
    unsigned short* zh = (unsigned short*)d_out;
    unsigned short* zl = zh + (size_t)N_ * C_;

    float*     zz       = (float*)d_ws;               // 131072
    float*     ee       = zz + N_;                    // 1024
    int*       idx_i    = (int*)(ee + K_);            // 131072
    uint32_t*  top3     = (uint32_t*)(idx_i + N_);    // 393216
    float*     partials = (float*)(top3 + (size_t)3 * N_); // 2048
    unsigned short* eh  = (unsigned short*)(partials + 2048); // 262144
    unsigned short* el  = eh + (size_t)K_ * C_;               // 262144

    esplit_kernel<<<128, 256, 0, stream>>>(emb, eh, el);
    ee_kernel<<<(K_ + 255)/256, 256, 0, stream>>>(emb, ee);
    zsplit_kernel<<<8192, 256, 0, stream>>>(z, zh, zl);
    zz_kernel<<<N_/256, 256, 0, stream>>>(z, zz);
    mfma_argmin_kernel<<<N_/128, 256, 0, stream>>>(zh, zl, eh, el, ee, top3);
    refine_kernel<<<N_/256, 256, 0, stream>>>(z, emb, zz, ee, top3, idx_i, idx_f);
    gather_kernel<<<2048, 256, 0, stream>>>(z, emb, idx_i, zq, partials);
    finalize_kernel<<<1, 256, 0, stream>>>(partials, 2048, loss);
}

// Round 5
// 719.336 us; speedup vs baseline: 2.1737x; 1.1116x over previous
//
#include <hip/hip_runtime.h>
#include <stdint.h>

#define B_   32
#define C_   256
#define HW_  4096
#define N_   131072   // B*H*W rows
#define K_   1024     // codebook size

typedef __attribute__((ext_vector_type(8))) short bf16x8;
typedef __attribute__((ext_vector_type(4))) float f32x4;

__device__ __forceinline__ unsigned short f2bf(float f) {
    unsigned int x = __float_as_uint(f);
    return (unsigned short)((x + 0x7FFFu + ((x >> 16) & 1u)) >> 16);   // RNE
}
__device__ __forceinline__ float bf2f(unsigned short h) {
    return __uint_as_float(((unsigned int)h) << 16);
}

#define GLD16(g, l) __builtin_amdgcn_global_load_lds((const __attribute__((address_space(1))) void*)(g), \
                        (__attribute__((address_space(3))) void*)(l), 16, 0, 0)

// ---------------- ||e_k||^2, replicating numpy pairwise_sum(256) ----------------
__global__ void ee_kernel(const float* __restrict__ emb, float* __restrict__ ee) {
#pragma clang fp contract(off)
    int k = blockIdx.x * blockDim.x + threadIdx.x;
    if (k >= K_) return;
    const float* e = emb + (size_t)k * C_;
    float res = 0.f;
    for (int h = 0; h < 2; ++h) {
        float r[8];
        #pragma unroll
        for (int j = 0; j < 8; ++j) { float v = e[h*128 + j]; r[j] = v * v; }
        for (int i = 8; i < 128; i += 8) {
            #pragma unroll
            for (int j = 0; j < 8; ++j) { float v = e[h*128 + i + j]; r[j] += v * v; }
        }
        float s = ((r[0] + r[1]) + (r[2] + r[3])) + ((r[4] + r[5]) + (r[6] + r[7]));
        res += s;
    }
    ee[k] = res;
}

// ---------------- emb -> bf16 hi/lo split, [k][c] layout ----------------
__global__ void esplit_kernel(const float* __restrict__ emb,
                              unsigned short* __restrict__ eh, unsigned short* __restrict__ el) {
    int t = blockIdx.x * 256 + threadIdx.x;            // 32768 threads
    int k = t >> 5, c8 = (t & 31) * 8;
    const float* src = emb + (size_t)k * C_ + c8;
    unsigned short hb[8], lb[8];
    #pragma unroll
    for (int i = 0; i < 8; ++i) {
        float f = src[i];
        unsigned short h = f2bf(f);
        hb[i] = h; lb[i] = f2bf(f - bf2f(h));
    }
    size_t off = (size_t)k * C_ + c8;
    *(uint4*)&eh[off] = *(uint4*)hb;
    *(uint4*)&el[off] = *(uint4*)lb;
}

// ---------------- z -> bf16 hi/lo split, TRANSPOSED to [n][c] layout ----------------
__global__ void zsplit_kernel(const float* __restrict__ z,
                              unsigned short* __restrict__ zh, unsigned short* __restrict__ zl) {
    __shared__ float t[64][65];
    int blk = blockIdx.x;
    int b = blk >> 8, ct = (blk >> 6) & 3, ht = blk & 63;
    int tid = threadIdx.x;
    int hw = tid & 63, c0 = tid >> 6;
    const float* src = z + ((size_t)b * C_ + ct * 64) * HW_ + ht * 64;
    #pragma unroll
    for (int k = 0; k < 16; ++k) {
        int c = k * 4 + c0;
        t[c][hw] = src[(size_t)c * HW_ + hw];
    }
    __syncthreads();
    int hw2 = tid >> 2, cs = (tid & 3) * 16;
    size_t off = ((size_t)b * HW_ + ht * 64 + hw2) * C_ + ct * 64 + cs;
    unsigned short hb[16], lb[16];
    #pragma unroll
    for (int i = 0; i < 16; ++i) {
        float f = t[cs + i][hw2];
        unsigned short h = f2bf(f);
        hb[i] = h; lb[i] = f2bf(f - bf2f(h));
    }
    *(uint4*)&zh[off]     = *(uint4*)&hb[0];
    *(uint4*)&zh[off + 8] = *(uint4*)&hb[8];
    *(uint4*)&zl[off]     = *(uint4*)&lb[0];
    *(uint4*)&zl[off + 8] = *(uint4*)&lb[8];
}

// ---------------- MFMA approx-distance + per-row top-3 shortlist ----------------
#define INS3(T, P) do { uint32_t _p = (P); \
    if (_p < T[2]) { if (_p < T[1]) { T[2] = T[1]; \
        if (_p < T[0]) { T[1] = T[0]; T[0] = _p; } else T[1] = _p; } else T[2] = _p; } } while (0)

__launch_bounds__(256)
__global__ void mfma_argmin_kernel(const unsigned short* __restrict__ zh, const unsigned short* __restrict__ zl,
                                   const unsigned short* __restrict__ eh, const unsigned short* __restrict__ el,
                                   const float* __restrict__ ee, uint32_t* __restrict__ top3) {
    __shared__ unsigned short Ah[128*32], Al[128*32], Bh[128*32], Bl[128*32];  // 32 KB
    __shared__ float eesh[K_];                                                 // 4 KB
    __shared__ uint32_t red[128][2][3];                                        // 3 KB

    const int tid = threadIdx.x;
    const int lane = tid & 63, wave = tid >> 6;
    const int wr = wave >> 1, wc = wave & 1;
    const int row0 = blockIdx.x * 128;

    for (int i = tid; i < K_; i += 256) eesh[i] = ee[i];

    uint32_t t3[16][3];
    #pragma unroll
    for (int s = 0; s < 16; ++s) { t3[s][0] = 0xFFFFFFFFu; t3[s][1] = 0xFFFFFFFFu; t3[s][2] = 0xFFFFFFFFu; }

    // T2 swizzle: logical c-seg k of row r stored at phys seg k ^ ((r>>1)&3).
    // GLD16 writes linearly -> apply inverse permutation on the GLOBAL source (rule #21).
    const int lr  = lane >> 2;                       // staging: row within 16-row group
    const int lc8 = (((lane & 3) ^ ((lr >> 1) & 3)) * 8);  // swizzled global c-seg (ushort offset)
    const int fr  = lane & 15;                       // frag row/col
    const int fk  = (((lane >> 4) ^ ((fr >> 1) & 3)) * 8); // swizzled phys seg for frag reads
    const int rb  = wave * 32;                       // this wave's 32-row staging slice

    __syncthreads();                    // eesh ready

    for (int kt = 0; kt < 8; ++kt) {
        f32x4 acc[4][4];
        #pragma unroll
        for (int m = 0; m < 4; ++m)
            #pragma unroll
            for (int n = 0; n < 4; ++n) acc[m][n] = (f32x4){0.f, 0.f, 0.f, 0.f};

        for (int c0 = 0; c0 < C_; c0 += 32) {
            size_t ga0 = (size_t)(row0 + rb + lr) * C_ + c0 + lc8;
            size_t ga1 = ga0 + (size_t)16 * C_;      // +16 rows: swizzle key unchanged (16 ≡ 0 mod 4)
            size_t gb0 = (size_t)(kt * 128 + rb + lr) * C_ + c0 + lc8;
            size_t gb1 = gb0 + (size_t)16 * C_;
            GLD16(zh + ga0, &Ah[(rb +  0) * 32]);
            GLD16(zh + ga1, &Ah[(rb + 16) * 32]);
            GLD16(zl + ga0, &Al[(rb +  0) * 32]);
            GLD16(zl + ga1, &Al[(rb + 16) * 32]);
            GLD16(eh + gb0, &Bh[(rb +  0) * 32]);
            GLD16(eh + gb1, &Bh[(rb + 16) * 32]);
            GLD16(el + gb0, &Bl[(rb +  0) * 32]);
            GLD16(el + gb1, &Bl[(rb + 16) * 32]);
            __syncthreads();

            bf16x8 ah[4], al4[4], bh[4], bl4[4];
            #pragma unroll
            for (int m = 0; m < 4; ++m) {
                int r = wr * 64 + m * 16 + fr;       // (r>>1)&3 == (fr>>1)&3 here
                ah[m]  = *(const bf16x8*)&Ah[r * 32 + fk];
                al4[m] = *(const bf16x8*)&Al[r * 32 + fk];
            }
            #pragma unroll
            for (int n = 0; n < 4; ++n) {
                int r = wc * 64 + n * 16 + fr;
                bh[n]  = *(const bf16x8*)&Bh[r * 32 + fk];
                bl4[n] = *(const bf16x8*)&Bl[r * 32 + fk];
            }
            #pragma unroll
            for (int m = 0; m < 4; ++m)
                #pragma unroll
                for (int n = 0; n < 4; ++n) {
                    acc[m][n] = __builtin_amdgcn_mfma_f32_16x16x32_bf16(ah[m],  bh[n],  acc[m][n], 0, 0, 0);
                    acc[m][n] = __builtin_amdgcn_mfma_f32_16x16x32_bf16(ah[m],  bl4[n], acc[m][n], 0, 0, 0);
                    acc[m][n] = __builtin_amdgcn_mfma_f32_16x16x32_bf16(al4[m], bh[n],  acc[m][n], 0, 0, 0);
                }
            __syncthreads();
        }

        // epilogue: d' = ee[col] - 2*dot, pack (sortable-float | col), keep per-row top3
        #pragma unroll
        for (int n = 0; n < 4; ++n) {
            int col = kt * 128 + wc * 64 + n * 16 + fr;
            float eev = eesh[col];
            #pragma unroll
            for (int m = 0; m < 4; ++m) {
                #pragma unroll
                for (int j = 0; j < 4; ++j) {
                    float d = eev - 2.0f * acc[m][n][j];
                    uint32_t bbits = __float_as_uint(d);
                    uint32_t u = bbits ^ (0x80000000u | (uint32_t)((int32_t)bbits >> 31));
                    uint32_t p = (u & 0xFFFFFC00u) | (uint32_t)col;
                    INS3(t3[m * 4 + j], p);
                }
            }
        }
    }

    // butterfly-merge top3 across the 16 lanes sharing each row
    #pragma unroll
    for (int st = 1; st < 16; st <<= 1) {
        #pragma unroll
        for (int s = 0; s < 16; ++s) {
            uint32_t q0 = __shfl_xor(t3[s][0], st, 64);
            uint32_t q1 = __shfl_xor(t3[s][1], st, 64);
            uint32_t q2 = __shfl_xor(t3[s][2], st, 64);
            INS3(t3[s], q0); INS3(t3[s], q1); INS3(t3[s], q2);
        }
    }
    if ((lane & 15) == 0) {
        int g = lane >> 4;
        #pragma unroll
        for (int m = 0; m < 4; ++m)
            #pragma unroll
            for (int j = 0; j < 4; ++j) {
                int r = wr * 64 + m * 16 + g * 4 + j;
                int s = m * 4 + j;
                red[r][wc][0] = t3[s][0]; red[r][wc][1] = t3[s][1]; red[r][wc][2] = t3[s][2];
            }
    }
    __syncthreads();
    if (tid < 128) {
        uint32_t a0 = red[tid][0][0], a1 = red[tid][0][1], a2 = red[tid][0][2];
        uint32_t b0 = red[tid][1][0], b1 = red[tid][1][1], b2 = red[tid][1][2];
        uint32_t o0, o1, o2;
        if (a0 <= b0) { o0 = a0;
            if (a1 <= b0) { o1 = a1; o2 = (a2 < b0 ? a2 : b0); }
            else          { o1 = b0; o2 = (a1 < b1 ? a1 : b1); }
        } else { o0 = b0;
            if (b1 <= a0) { o1 = b1; o2 = (b2 < a0 ? b2 : a0); }
            else          { o1 = a0; o2 = (a1 < b1 ? a1 : b1); }
        }
        uint32_t* dst = top3 + (size_t)(row0 + tid) * 3;
        dst[0] = o0; dst[1] = o1; dst[2] = o2;
    }
}

// ---------------- exact refine on top-3, zz fused (numpy pairwise order) ----------------
__launch_bounds__(256)
__global__ void refine_kernel(const float* __restrict__ z, const float* __restrict__ emb,
                              const float* __restrict__ ee, const uint32_t* __restrict__ top3,
                              int* __restrict__ idx_i, float* __restrict__ idx_f) {
#pragma clang fp contract(off)
    int n = blockIdx.x * 256 + threadIdx.x;
    int b = n >> 12, hw = n & 4095;
    int c0 = (int)(top3[(size_t)n * 3 + 0] & 0x3FFu);
    int c1 = (int)(top3[(size_t)n * 3 + 1] & 0x3FFu);
    int c2 = (int)(top3[(size_t)n * 3 + 2] & 0x3FFu);
    int t;
    if (c1 < c0) { t = c0; c0 = c1; c1 = t; }
    if (c2 < c1) { t = c1; c1 = c2; c2 = t; }
    if (c1 < c0) { t = c0; c0 = c1; c1 = t; }
    const float* zp = z + (size_t)b * C_ * HW_ + hw;
    const float4* e0 = (const float4*)(emb + (size_t)c0 * C_);
    const float4* e1 = (const float4*)(emb + (size_t)c1 * C_);
    const float4* e2 = (const float4*)(emb + (size_t)c2 * C_);
    float a0 = 0.f, a1 = 0.f, a2 = 0.f;     // fmaf chains, ascending c (round-4-identical)
    float zzr = 0.f;                        // numpy pairwise ||z||^2, fused

    #pragma unroll
    for (int half = 0; half < 2; ++half) {
        float r[8];
        // c4l = 0,1 initialize r[0..7]; c4l = 2..31 accumulate (v*v then add: contract off)
        #pragma unroll 2
        for (int c4l = 0; c4l < 2; ++c4l) {
            int c4 = half * 32 + c4l;
            float4 v0 = e0[c4], v1 = e1[c4], v2 = e2[c4];
            #pragma unroll
            for (int i = 0; i < 4; ++i) {
                int c = c4 * 4 + i;
                float zv = zp[(size_t)c * HW_];
                r[c4l * 4 + i] = zv * zv;
                a0 = fmaf(zv, ((const float*)&v0)[i], a0);
                a1 = fmaf(zv, ((const float*)&v1)[i], a1);
                a2 = fmaf(zv, ((const float*)&v2)[i], a2);
            }
        }
        #pragma unroll 6
        for (int c4l = 2; c4l < 32; ++c4l) {
            int c4 = half * 32 + c4l;
            float4 v0 = e0[c4], v1 = e1[c4], v2 = e2[c4];
            #pragma unroll
            for (int i = 0; i < 4; ++i) {
                int c = c4 * 4 + i;
                float zv = zp[(size_t)c * HW_];
                float sq = zv * zv;
                int j = (c4l * 4 + i) & 7;
                r[j] = r[j] + sq;
                a0 = fmaf(zv, ((const float*)&v0)[i], a0);
                a1 = fmaf(zv, ((const float*)&v1)[i], a1);
                a2 = fmaf(zv, ((const float*)&v2)[i], a2);
            }
        }
        float s = ((r[0] + r[1]) + (r[2] + r[3])) + ((r[4] + r[5]) + (r[6] + r[7]));
        zzr = zzr + s;                      // half0: 0+sA (exact); half1: sA+sB  == ref
    }

    float A0 = zzr + ee[c0]; float d0 = A0 - 2.0f * a0;
    float A1 = zzr + ee[c1]; float d1 = A1 - 2.0f * a1;
    float A2 = zzr + ee[c2]; float d2 = A2 - 2.0f * a2;
    float bv = d0; int bi = c0;
    if (c1 != c0 && d1 < bv) { bv = d1; bi = c1; }
    if (c2 != c1 && c2 != c0 && d2 < bv) { bv = d2; bi = c2; }
    idx_i[n] = bi;
    idx_f[n] = (float)bi;
}

// ---------------- gather zq_st (straight-through) + loss partials ----------------
__global__ void gather_kernel(const float* __restrict__ z, const float* __restrict__ emb,
                              const int* __restrict__ idx, float* __restrict__ zq,
                              float* __restrict__ partials) {
#pragma clang fp contract(off)
    const long long TOT = (long long)N_ * (C_/4);
    float ls = 0.f;
    for (long long g = (long long)blockIdx.x * blockDim.x + threadIdx.x; g < TOT;
         g += (long long)gridDim.x * blockDim.x) {
        int c4 = (int)(g >> 17);
        int n  = (int)(g & (N_ - 1));
        int b = n >> 12, hw = n & 4095;
        int j = idx[n];
        float4 e4 = *(const float4*)&emb[(size_t)j * C_ + c4*4];
        size_t base = (size_t)b * C_ * HW_ + (size_t)(c4*4) * HW_ + hw;
        float zv, df;
        zv = z[base + 0*HW_]; df = e4.x - zv; zq[base + 0*HW_] = zv + df; ls += df*df;
        zv = z[base + 1*HW_]; df = e4.y - zv; zq[base + 1*HW_] = zv + df; ls += df*df;
        zv = z[base + 2*HW_]; df = e4.z - zv; zq[base + 2*HW_] = zv + df; ls += df*df;
        zv = z[base + 3*HW_]; df = e4.w - zv; zq[base + 3*HW_] = zv + df; ls += df*df;
    }
    __shared__ float sred[256];
    sred[threadIdx.x] = ls;
    __syncthreads();
    for (int s = 128; s > 0; s >>= 1) {
        if (threadIdx.x < s) sred[threadIdx.x] += sred[threadIdx.x + s];
        __syncthreads();
    }
    if (threadIdx.x == 0) partials[blockIdx.x] = sred[0];
}

__global__ void finalize_kernel(const float* __restrict__ partials, int nparts,
                                float* __restrict__ loss_out) {
    __shared__ float sred[256];
    float s = 0.f;
    for (int i = threadIdx.x; i < nparts; i += 256) s += partials[i];
    sred[threadIdx.x] = s; __syncthreads();
    for (int st = 128; st > 0; st >>= 1) {
        if (threadIdx.x < st) sred[threadIdx.x] += sred[threadIdx.x + st];
        __syncthreads();
    }
    if (threadIdx.x == 0) {
        float m = sred[0] / 33554432.0f;
        *loss_out = m - 0.25f * m;
    }
}

extern "C" void kernel_launch(void* const* d_in, const int* in_sizes, int n_in,
                              void* d_out, int out_size, void* d_ws, size_t ws_size,
                              hipStream_t stream) {
    const float* z   = (const float*)d_in[0];
    const float* emb = (const float*)d_in[1];
    float* out   = (float*)d_out;
    float* zq    = out;                        // 33554432 floats
    float* idx_f = out + (size_t)N_ * C_;      // 131072
    float* loss  = idx_f + N_;                 // 1

    // zh/zl (bf16, [n][c]) live in the zq region (exactly 134 MB); gather overwrites later.
    unsigned short* zh = (unsigned short*)d_out;
    unsigned short* zl = zh + (size_t)N_ * C_;

    float*     ee       = (float*)d_ws;               // 1024
    int*       idx_i    = (int*)(ee + K_);            // 131072
    uint32_t*  top3     = (uint32_t*)(idx_i + N_);    // 393216
    float*     partials = (float*)(top3 + (size_t)3 * N_); // 2048
    unsigned short* eh  = (unsigned short*)(partials + 2048); // 262144
    unsigned short* el  = eh + (size_t)K_ * C_;               // 262144

    esplit_kernel<<<128, 256, 0, stream>>>(emb, eh, el);
    ee_kernel<<<(K_ + 255)/256, 256, 0, stream>>>(emb, ee);
    zsplit_kernel<<<8192, 256, 0, stream>>>(z, zh, zl);
    mfma_argmin_kernel<<<N_/128, 256, 0, stream>>>(zh, zl, eh, el, ee, top3);
    refine_kernel<<<N_/256, 256, 0, stream>>>(z, emb, ee, top3, idx_i, idx_f);
    gather_kernel<<<2048, 256, 0, stream>>>(z, emb, idx_i, zq, partials);
    finalize_kernel<<<1, 256, 0, stream>>>(partials, 2048, loss);
}